// Round 2
// baseline (8223.154 us; speedup 1.0000x reference)
//
#include <hip/hip_runtime.h>
#include <math.h>

// LSTMPredictor: B=2048 rows, 3x LSTMCell(H=50), P=17, T=512 + 32 future steps.
// fp32 buffers (runtime-sniffed, bf16 fallback kept). One block per CU owns M=8
// batch rows for the whole 544-step recurrence.
//
// R1 restructure: thread = (single gate g, K-fifth q), 1000/1024 active;
// per-thread weights 54 floats; gb relaid [q][gate][m].
// R2 fix: __launch_bounds__(1024, 2) -- R1's (1024,4) made the compiler cap
// VGPRs at 64, spilling the 54 weight floats to scratch (FETCH_SIZE 45MB->24GB,
// VALUBusy 43->15%, 2.1x regression). Budget 256 lets the ~110 live regs stay
// in VGPRs; HW still runs 4 waves/SIMD at <=128 VGPRs so occupancy ~48% holds.

#define BATCH    2048
#define PP       17
#define HH       50
#define GG       200      // 4*H
#define MROWS    8
#define NQ       5        // K split into fifths
#define NTHREADS 1024
#define NBLOCKS  (BATCH / MROWS)   // 256
#define TQ1      14       // cell1 K=68 (x17 + h50 + pad) -> 5*14=70
#define TQ2      20       // cell2 K=100 exact
#define TQ3      20       // cell3 K=100 exact

__device__ __forceinline__ float bf2f(unsigned short u) {
    unsigned int i = ((unsigned int)u) << 16;
    float f; __builtin_memcpy(&f, &i, 4); return f;
}
__device__ __forceinline__ unsigned short f2bf(float f) {
    unsigned int i; __builtin_memcpy(&i, &f, 4);
    return (unsigned short)((i + 0x7fffu + ((i >> 16) & 1u)) >> 16);
}
__device__ __forceinline__ float ldin(const void* p, long i, bool f32) {
    return f32 ? ((const float*)p)[i] : bf2f(((const unsigned short*)p)[i]);
}
// saturation-safe fast sigmoid/tanh (v_exp_f32 + v_rcp_f32)
__device__ __forceinline__ float fsig(float x) {
    float t = exp2f(-1.44269504089f * x);          // +inf at x->-inf, 0 at x->+inf
    return __builtin_amdgcn_rcpf(1.0f + t);        // 0 / 1 at the limits
}
__device__ __forceinline__ float ftanh(float x) {
    float t = exp2f(2.88539008178f * x);           // e^(2x)
    return 1.0f - 2.0f * __builtin_amdgcn_rcpf(t + 1.0f);   // -1 / +1 at the limits
}

// ---- dtype sniffer: bf16 weights decode to |v|<=0.142; fp32-as-bf16 gives junk ----
extern "C" __global__ void sniff_dtype(const unsigned short* __restrict__ w,
                                       int* __restrict__ flag) {
    int lane = threadIdx.x;
    bool bad = false;
#pragma unroll
    for (int t = 0; t < 4; ++t) {
        float v = bf2f(w[lane * 4 + t]);
        bad |= !(fabsf(v) <= 1.0f);
    }
    unsigned long long m = __ballot(bad);
    if (lane == 0) flag[0] = (m != 0ULL) ? 1 : 0;   // 1 => fp32 buffers
}

// gate phase: thread (g, q) accumulates the K-fifth partial of gate g for all
// 8 rows. Weights in registers; state reads are wave-uniform LDS broadcasts
// (2-address gather in the 4 fifth-boundary waves).
template <int TQ>
__device__ __forceinline__ void gate_phase(const float* __restrict__ S,
                                           float* __restrict__ gb,
                                           const float w[TQ],
                                           int srow, int g, int q, bool active) {
    if (active) {
        float a[8] = {0, 0, 0, 0, 0, 0, 0, 0};
        const float4* Sp = (const float4*)(S + (srow + q * TQ) * MROWS);
#pragma unroll
        for (int t = 0; t < TQ; ++t) {
            float wv = w[t];
            float4 lo = Sp[2 * t];         // broadcast read (rows m=0..3)
            float4 hi = Sp[2 * t + 1];     // rows m=4..7
            a[0] = fmaf(wv, lo.x, a[0]); a[1] = fmaf(wv, lo.y, a[1]);
            a[2] = fmaf(wv, lo.z, a[2]); a[3] = fmaf(wv, lo.w, a[3]);
            a[4] = fmaf(wv, hi.x, a[4]); a[5] = fmaf(wv, hi.y, a[5]);
            a[6] = fmaf(wv, hi.z, a[6]); a[7] = fmaf(wv, hi.w, a[7]);
        }
        // gb[q][g][m]: m contiguous -> two b128 stores
        float4* d = (float4*)(gb + (q * GG + g) * MROWS);
        d[0] = make_float4(a[0], a[1], a[2], a[3]);
        d[1] = make_float4(a[4], a[5], a[6], a[7]);
    }
}

__device__ __forceinline__ void lstm_update(float* __restrict__ S,
                                            const float* __restrict__ gb,
                                            const float* __restrict__ bs,
                                            float& c, int hrow, int tid) {
    // caller guards tid < 400;  m = tid&7 (conflict-free h write), j = tid>>3
    int m = tid & 7;
    int j = tid >> 3;
    float ii = bs[j], ff = bs[50 + j], gg = bs[100 + j], oo = bs[150 + j];
#pragma unroll
    for (int q = 0; q < NQ; ++q) {
        // addr%32 == lane within each read -> conflict-free
        const float* b = gb + q * (GG * MROWS) + m;
        ii += b[j * 8]; ff += b[(50 + j) * 8];
        gg += b[(100 + j) * 8]; oo += b[(150 + j) * 8];
    }
    float cn = fsig(ff) * c + fsig(ii) * ftanh(gg);
    c = cn;
    S[(hrow + j) * MROWS + m] = fsig(oo) * ftanh(cn);   // addr = hrow*8 + tid
}

extern "C" __global__ void __launch_bounds__(NTHREADS, 2)
lstm_persistent(const void* __restrict__ x,
                const void* __restrict__ wih1, const void* __restrict__ whh1,
                const void* __restrict__ bih1, const void* __restrict__ bhh1,
                const void* __restrict__ wih2, const void* __restrict__ whh2,
                const void* __restrict__ bih2, const void* __restrict__ bhh2,
                const void* __restrict__ wih3, const void* __restrict__ whh3,
                const void* __restrict__ bih3, const void* __restrict__ bhh3,
                const void* __restrict__ wlin, const void* __restrict__ blin,
                void* __restrict__ out, const int* __restrict__ flag,
                int T, int steps)
{
    const int tid = threadIdx.x;
    __shared__ float S[167 * MROWS];        // 0..16 x | 17..66 h1 | 67..116 h2 | 117..166 h3
    __shared__ float gb[NQ * GG * MROWS];   // [fifth][gate][m]  (32 KB)
    __shared__ float WLt[50 * PP];          // W_lin^T
    __shared__ float bs1[GG], bs2[GG], bs3[GG], bl[PP];

    const bool f32 = (flag[0] != 0);

    const int q = tid / GG;                 // K-fifth (wave-uniform except 4 boundary waves)
    const int g = tid - q * GG;             // gate index 0..199
    const bool active = (tid < NQ * GG);    // 1000 of 1024

    // ---- per-thread register weights (fp32, full precision): 54 floats ----
    float w1[TQ1], w2[TQ2], w3[TQ3];
    if (active) {
#pragma unroll
        for (int t = 0; t < TQ1; ++t) {              // cell1 K=68 (rows 68,69 zero-pad)
            int k = q * TQ1 + t;
            w1[t] = (k < 17) ? ldin(wih1, (long)g * 17 + k, f32)
                  : (k < 67) ? ldin(whh1, (long)g * 50 + (k - 17), f32)
                             : 0.0f;
        }
#pragma unroll
        for (int t = 0; t < TQ2; ++t) {              // cell2 K=100
            int k = q * TQ2 + t;
            w2[t] = (k < 50) ? ldin(wih2, (long)g * 50 + k, f32)
                             : ldin(whh2, (long)g * 50 + (k - 50), f32);
        }
#pragma unroll
        for (int t = 0; t < TQ3; ++t) {              // cell3 K=100
            int k = q * TQ3 + t;
            w3[t] = (k < 50) ? ldin(wih3, (long)g * 50 + k, f32)
                             : ldin(whh3, (long)g * 50 + (k - 50), f32);
        }
    }

    // ---- stage biases, W_lin^T, zero h-state, preload x(step 0) ----
    if (tid < GG) {
        bs1[tid] = ldin(bih1, tid, f32) + ldin(bhh1, tid, f32);
        bs2[tid] = ldin(bih2, tid, f32) + ldin(bhh2, tid, f32);
        bs3[tid] = ldin(bih3, tid, f32) + ldin(bhh3, tid, f32);
    } else if (tid < GG + PP) {
        bl[tid - GG] = ldin(blin, tid - GG, f32);
    }
    for (int i = tid; i < 50 * PP; i += NTHREADS) {
        int k = i / PP, p = i - k * PP;
        WLt[i] = ldin(wlin, (long)p * 50 + k, f32);
    }
    for (int i = tid; i < 1200; i += NTHREADS) S[136 + i] = 0.0f;   // h1,h2,h3 = 0

    const long rowBase = (long)blockIdx.x * MROWS;
    const long xStride = (long)T * PP;
    if (tid < 136) {
        int m = tid / PP, p = tid - (tid / PP) * PP;
        S[p * MROWS + m] = ldin(x, (rowBase + m) * xStride + p, f32);
    }
    float c1 = 0.0f, c2 = 0.0f, c3 = 0.0f;
    __syncthreads();

    const long outStride = (long)steps * PP;
    for (int s = 0; s < steps; ++s) {
        gate_phase<TQ1>(S, gb, w1, 0, g, q, active);            // cell1: [x|h1]
        __syncthreads();
        if (tid < 400) lstm_update(S, gb, bs1, c1, 17, tid);    // write h1
        __syncthreads();
        gate_phase<TQ2>(S, gb, w2, 17, g, q, active);           // cell2: [h1|h2]
        __syncthreads();
        if (tid < 400) lstm_update(S, gb, bs2, c2, 67, tid);    // write h2
        __syncthreads();
        gate_phase<TQ3>(S, gb, w3, 67, g, q, active);           // cell3: [h2|h3]
        __syncthreads();
        if (tid < 400) lstm_update(S, gb, bs3, c3, 117, tid);   // write h3
        __syncthreads();
        // ---- linear head + output + next input (feedback or global x) ----
        if (tid < 136) {
            int m = tid / PP, p = tid - (tid / PP) * PP;
            float acc = bl[p];
#pragma unroll
            for (int k = 0; k < 50; ++k)
                acc = fmaf(WLt[k * PP + p], S[(117 + k) * MROWS + m], acc);
            long oi = (rowBase + m) * outStride + (long)s * PP + p;
            if (f32) ((float*)out)[oi] = acc;
            else     ((unsigned short*)out)[oi] = f2bf(acc);
            if (s + 1 >= T && s + 1 < steps)                    // autoregressive feedback
                S[p * MROWS + m] = acc;
        } else if (tid >= 256 && tid < 392) {
            int u = tid - 256;
            int m = u / PP, p = u - (u / PP) * PP;
            if (s + 1 < T)                                      // prefetch next x chunk
                S[p * MROWS + m] = ldin(x, (rowBase + m) * xStride + (long)(s + 1) * PP + p, f32);
        }
        __syncthreads();
    }
}

extern "C" void kernel_launch(void* const* d_in, const int* in_sizes, int n_in,
                              void* d_out, int out_size, void* d_ws, size_t ws_size,
                              hipStream_t stream) {
    (void)ws_size; (void)n_in;
    int* flag = (int*)d_ws;

    const int T     = in_sizes[0] / (BATCH * PP);   // 512
    const int steps = out_size / (BATCH * PP);      // 544

    sniff_dtype<<<1, 64, 0, stream>>>((const unsigned short*)d_in[1], flag);

    lstm_persistent<<<NBLOCKS, NTHREADS, 0, stream>>>(
        d_in[0],
        d_in[1], d_in[2], d_in[3], d_in[4],
        d_in[5], d_in[6], d_in[7], d_in[8],
        d_in[9], d_in[10], d_in[11], d_in[12],
        d_in[13], d_in[14],
        d_out, flag, T, steps);
}

// Round 3
// 3529.506 us; speedup vs baseline: 2.3298x; 2.3298x over previous
//
#include <hip/hip_runtime.h>
#include <math.h>

// LSTMPredictor: B=2048 rows, 3x LSTMCell(H=50), P=17, T=512 + 32 future steps.
// fp32 buffers (runtime-sniffed, bf16 fallback kept). One block per CU owns M=8
// batch rows for the whole 544-step recurrence.
//
// R1 restructure: thread = (single gate g, K-fifth q), 1000/1024 active;
// per-thread weights 54 floats.
// R2 lesson: with a 1024-thread workgroup hipcc pins the allocator at 64 VGPRs
// no matter what __launch_bounds__'s 2nd arg says (tried 4 and 2; both -> 64
// VGPRs, 54 weight floats spilled to scratch, FETCH_SIZE 23.7 GB, 8.2 ms).
// R3 fix A: set the backend attrs directly -- amdgpu_waves_per_eu(4,4) +
//   amdgpu_flat_work_group_size(1024,1024) -> budget 512/4 = 128 VGPRs.
//   (4 waves/EU is what 1 resident 16-wave block gives anyway; 2 blocks/CU is
//   impossible at >64 VGPRs, so nothing is lost.)
// R3 fix B: gb relaid [q][m][gate] -- the old [q][gate][m] made gate-phase
//   ds_write_b128 stride 32B across lanes (16-way bank conflict, 1.07e8
//   conflict cycles). Now: 8 scalar ds_write_b32 at lane-consecutive addrs
//   (conflict-free); update reads land (8m+j)%32 = 2-way (free).

#define BATCH    2048
#define PP       17
#define HH       50
#define GG       200      // 4*H
#define MROWS    8
#define NQ       5        // K split into fifths
#define NTHREADS 1024
#define NBLOCKS  (BATCH / MROWS)   // 256
#define TQ1      14       // cell1 K=68 (x17 + h50 + pad) -> 5*14=70
#define TQ2      20       // cell2 K=100 exact
#define TQ3      20       // cell3 K=100 exact

__device__ __forceinline__ float bf2f(unsigned short u) {
    unsigned int i = ((unsigned int)u) << 16;
    float f; __builtin_memcpy(&f, &i, 4); return f;
}
__device__ __forceinline__ unsigned short f2bf(float f) {
    unsigned int i; __builtin_memcpy(&i, &f, 4);
    return (unsigned short)((i + 0x7fffu + ((i >> 16) & 1u)) >> 16);
}
__device__ __forceinline__ float ldin(const void* p, long i, bool f32) {
    return f32 ? ((const float*)p)[i] : bf2f(((const unsigned short*)p)[i]);
}
// saturation-safe fast sigmoid/tanh (v_exp_f32 + v_rcp_f32)
__device__ __forceinline__ float fsig(float x) {
    float t = exp2f(-1.44269504089f * x);          // +inf at x->-inf, 0 at x->+inf
    return __builtin_amdgcn_rcpf(1.0f + t);        // 0 / 1 at the limits
}
__device__ __forceinline__ float ftanh(float x) {
    float t = exp2f(2.88539008178f * x);           // e^(2x)
    return 1.0f - 2.0f * __builtin_amdgcn_rcpf(t + 1.0f);   // -1 / +1 at the limits
}

// ---- dtype sniffer: bf16 weights decode to |v|<=0.142; fp32-as-bf16 gives junk ----
extern "C" __global__ void sniff_dtype(const unsigned short* __restrict__ w,
                                       int* __restrict__ flag) {
    int lane = threadIdx.x;
    bool bad = false;
#pragma unroll
    for (int t = 0; t < 4; ++t) {
        float v = bf2f(w[lane * 4 + t]);
        bad |= !(fabsf(v) <= 1.0f);
    }
    unsigned long long m = __ballot(bad);
    if (lane == 0) flag[0] = (m != 0ULL) ? 1 : 0;   // 1 => fp32 buffers
}

// gate phase: thread (g, q) accumulates the K-fifth partial of gate g for all
// 8 rows. Weights in registers; state reads are wave-uniform LDS broadcasts
// (2-address gather in the 4 fifth-boundary waves).
template <int TQ>
__device__ __forceinline__ void gate_phase(const float* __restrict__ S,
                                           float* __restrict__ gb,
                                           const float w[TQ],
                                           int srow, int g, int q, bool active) {
    if (active) {
        float a[8] = {0, 0, 0, 0, 0, 0, 0, 0};
        const float4* Sp = (const float4*)(S + (srow + q * TQ) * MROWS);
#pragma unroll
        for (int t = 0; t < TQ; ++t) {
            float wv = w[t];
            float4 lo = Sp[2 * t];         // broadcast read (rows m=0..3)
            float4 hi = Sp[2 * t + 1];     // rows m=4..7
            a[0] = fmaf(wv, lo.x, a[0]); a[1] = fmaf(wv, lo.y, a[1]);
            a[2] = fmaf(wv, lo.z, a[2]); a[3] = fmaf(wv, lo.w, a[3]);
            a[4] = fmaf(wv, hi.x, a[4]); a[5] = fmaf(wv, hi.y, a[5]);
            a[6] = fmaf(wv, hi.z, a[6]); a[7] = fmaf(wv, hi.w, a[7]);
        }
        // gb[q][m][g]: lane-consecutive scalar stores -> conflict-free
        float* d = gb + (q * MROWS) * GG + g;
#pragma unroll
        for (int m = 0; m < 8; ++m) d[m * GG] = a[m];
    }
}

__device__ __forceinline__ void lstm_update(float* __restrict__ S,
                                            const float* __restrict__ gb,
                                            const float* __restrict__ bs,
                                            float& c, int hrow, int tid) {
    // caller guards tid < 400;  m = tid&7 (conflict-free h write), j = tid>>3
    int m = tid & 7;
    int j = tid >> 3;
    float ii = bs[j], ff = bs[50 + j], gg = bs[100 + j], oo = bs[150 + j];
#pragma unroll
    for (int q = 0; q < NQ; ++q) {
        // addr%32 = (8m+j)%32 across the wave -> 2-way (free)
        const float* b = gb + (q * MROWS + m) * GG;
        ii += b[j]; ff += b[50 + j]; gg += b[100 + j]; oo += b[150 + j];
    }
    float cn = fsig(ff) * c + fsig(ii) * ftanh(gg);
    c = cn;
    S[(hrow + j) * MROWS + m] = fsig(oo) * ftanh(cn);   // addr = hrow*8 + tid
}

extern "C" __global__
__attribute__((amdgpu_flat_work_group_size(NTHREADS, NTHREADS)))
__attribute__((amdgpu_waves_per_eu(4, 4)))
void lstm_persistent(const void* __restrict__ x,
                const void* __restrict__ wih1, const void* __restrict__ whh1,
                const void* __restrict__ bih1, const void* __restrict__ bhh1,
                const void* __restrict__ wih2, const void* __restrict__ whh2,
                const void* __restrict__ bih2, const void* __restrict__ bhh2,
                const void* __restrict__ wih3, const void* __restrict__ whh3,
                const void* __restrict__ bih3, const void* __restrict__ bhh3,
                const void* __restrict__ wlin, const void* __restrict__ blin,
                void* __restrict__ out, const int* __restrict__ flag,
                int T, int steps)
{
    const int tid = threadIdx.x;
    __shared__ float S[167 * MROWS];        // 0..16 x | 17..66 h1 | 67..116 h2 | 117..166 h3
    __shared__ float gb[NQ * MROWS * GG];   // [fifth][m][gate]  (32 KB)
    __shared__ float WLt[50 * PP];          // W_lin^T
    __shared__ float bs1[GG], bs2[GG], bs3[GG], bl[PP];

    const bool f32 = (flag[0] != 0);

    const int q = tid / GG;                 // K-fifth (wave-uniform except 4 boundary waves)
    const int g = tid - q * GG;             // gate index 0..199
    const bool active = (tid < NQ * GG);    // 1000 of 1024

    // ---- per-thread register weights (fp32, full precision): 54 floats ----
    float w1[TQ1], w2[TQ2], w3[TQ3];
    if (active) {
#pragma unroll
        for (int t = 0; t < TQ1; ++t) {              // cell1 K=68 (rows 68,69 zero-pad)
            int k = q * TQ1 + t;
            w1[t] = (k < 17) ? ldin(wih1, (long)g * 17 + k, f32)
                  : (k < 67) ? ldin(whh1, (long)g * 50 + (k - 17), f32)
                             : 0.0f;
        }
#pragma unroll
        for (int t = 0; t < TQ2; ++t) {              // cell2 K=100
            int k = q * TQ2 + t;
            w2[t] = (k < 50) ? ldin(wih2, (long)g * 50 + k, f32)
                             : ldin(whh2, (long)g * 50 + (k - 50), f32);
        }
#pragma unroll
        for (int t = 0; t < TQ3; ++t) {              // cell3 K=100
            int k = q * TQ3 + t;
            w3[t] = (k < 50) ? ldin(wih3, (long)g * 50 + k, f32)
                             : ldin(whh3, (long)g * 50 + (k - 50), f32);
        }
    }

    // ---- stage biases, W_lin^T, zero h-state, preload x(step 0) ----
    if (tid < GG) {
        bs1[tid] = ldin(bih1, tid, f32) + ldin(bhh1, tid, f32);
        bs2[tid] = ldin(bih2, tid, f32) + ldin(bhh2, tid, f32);
        bs3[tid] = ldin(bih3, tid, f32) + ldin(bhh3, tid, f32);
    } else if (tid < GG + PP) {
        bl[tid - GG] = ldin(blin, tid - GG, f32);
    }
    for (int i = tid; i < 50 * PP; i += NTHREADS) {
        int k = i / PP, p = i - k * PP;
        WLt[i] = ldin(wlin, (long)p * 50 + k, f32);
    }
    for (int i = tid; i < 1200; i += NTHREADS) S[136 + i] = 0.0f;   // h1,h2,h3 = 0

    const long rowBase = (long)blockIdx.x * MROWS;
    const long xStride = (long)T * PP;
    if (tid < 136) {
        int m = tid / PP, p = tid - (tid / PP) * PP;
        S[p * MROWS + m] = ldin(x, (rowBase + m) * xStride + p, f32);
    }
    float c1 = 0.0f, c2 = 0.0f, c3 = 0.0f;
    __syncthreads();

    const long outStride = (long)steps * PP;
    for (int s = 0; s < steps; ++s) {
        gate_phase<TQ1>(S, gb, w1, 0, g, q, active);            // cell1: [x|h1]
        __syncthreads();
        if (tid < 400) lstm_update(S, gb, bs1, c1, 17, tid);    // write h1
        __syncthreads();
        gate_phase<TQ2>(S, gb, w2, 17, g, q, active);           // cell2: [h1|h2]
        __syncthreads();
        if (tid < 400) lstm_update(S, gb, bs2, c2, 67, tid);    // write h2
        __syncthreads();
        gate_phase<TQ3>(S, gb, w3, 67, g, q, active);           // cell3: [h2|h3]
        __syncthreads();
        if (tid < 400) lstm_update(S, gb, bs3, c3, 117, tid);   // write h3
        __syncthreads();
        // ---- linear head + output + next input (feedback or global x) ----
        if (tid < 136) {
            int m = tid / PP, p = tid - (tid / PP) * PP;
            float acc = bl[p];
#pragma unroll
            for (int k = 0; k < 50; ++k)
                acc = fmaf(WLt[k * PP + p], S[(117 + k) * MROWS + m], acc);
            long oi = (rowBase + m) * outStride + (long)s * PP + p;
            if (f32) ((float*)out)[oi] = acc;
            else     ((unsigned short*)out)[oi] = f2bf(acc);
            if (s + 1 >= T && s + 1 < steps)                    // autoregressive feedback
                S[p * MROWS + m] = acc;
        } else if (tid >= 256 && tid < 392) {
            int u = tid - 256;
            int m = u / PP, p = u - (u / PP) * PP;
            if (s + 1 < T)                                      // prefetch next x chunk
                S[p * MROWS + m] = ldin(x, (rowBase + m) * xStride + (long)(s + 1) * PP + p, f32);
        }
        __syncthreads();
    }
}

extern "C" void kernel_launch(void* const* d_in, const int* in_sizes, int n_in,
                              void* d_out, int out_size, void* d_ws, size_t ws_size,
                              hipStream_t stream) {
    (void)ws_size; (void)n_in;
    int* flag = (int*)d_ws;

    const int T     = in_sizes[0] / (BATCH * PP);   // 512
    const int steps = out_size / (BATCH * PP);      // 544

    sniff_dtype<<<1, 64, 0, stream>>>((const unsigned short*)d_in[1], flag);

    lstm_persistent<<<NBLOCKS, NTHREADS, 0, stream>>>(
        d_in[0],
        d_in[1], d_in[2], d_in[3], d_in[4],
        d_in[5], d_in[6], d_in[7], d_in[8],
        d_in[9], d_in[10], d_in[11], d_in[12],
        d_in[13], d_in[14],
        d_out, flag, T, steps);
}

// Round 4
// 3427.483 us; speedup vs baseline: 2.3992x; 1.0298x over previous
//
#include <hip/hip_runtime.h>
#include <math.h>

// LSTMPredictor: B=2048 rows, 3x LSTMCell(H=50), P=17, T=512 + 32 future steps.
// fp32 buffers (runtime-sniffed, bf16 fallback kept). One block per CU owns M=8
// batch rows for the whole 544-step recurrence.
//
// R1: thread = (single gate g, K-fifth q), 1000/1024 active; 54 weight floats.
// R2 lesson: __launch_bounds__ 2nd arg can't raise the 64-VGPR cap at 1024 thr.
// R3: amdgpu_waves_per_eu(4,4) -> budget 128; spill gone (FETCH 24GB->36MB),
//     3530 us. BUT VGPR_Count=52: allocator parked arrays in AGPRs, and the
//     VALU-busy count (10.0k cyc/SIMD/step vs 3.4k of real FMA issue, 2.35x)
//     matches accumulators living in AGPRs: each fmaf = accvgpr_read + fma +
//     accvgpr_write = 3 VALU ops.
// R4: pin gate-phase accumulators in arch VGPRs via inline v_fmac_f32 with
//     "+v"/"v" constraints (bit-identical fused mac). Weights may stay in AGPR
//     (1 accvgpr_read per 8 fmas -- 1.6%). Predicted: VGPR>=80, dur ~2.1-2.7ms.

#define BATCH    2048
#define PP       17
#define HH       50
#define GG       200      // 4*H
#define MROWS    8
#define NQ       5        // K split into fifths
#define NTHREADS 1024
#define NBLOCKS  (BATCH / MROWS)   // 256
#define TQ1      14       // cell1 K=68 (x17 + h50 + pad) -> 5*14=70
#define TQ2      20       // cell2 K=100 exact
#define TQ3      20       // cell3 K=100 exact

__device__ __forceinline__ float bf2f(unsigned short u) {
    unsigned int i = ((unsigned int)u) << 16;
    float f; __builtin_memcpy(&f, &i, 4); return f;
}
__device__ __forceinline__ unsigned short f2bf(float f) {
    unsigned int i; __builtin_memcpy(&i, &f, 4);
    return (unsigned short)((i + 0x7fffu + ((i >> 16) & 1u)) >> 16);
}
__device__ __forceinline__ float ldin(const void* p, long i, bool f32) {
    return f32 ? ((const float*)p)[i] : bf2f(((const unsigned short*)p)[i]);
}
// saturation-safe fast sigmoid/tanh (v_exp_f32 + v_rcp_f32)
__device__ __forceinline__ float fsig(float x) {
    float t = exp2f(-1.44269504089f * x);          // +inf at x->-inf, 0 at x->+inf
    return __builtin_amdgcn_rcpf(1.0f + t);        // 0 / 1 at the limits
}
__device__ __forceinline__ float ftanh(float x) {
    float t = exp2f(2.88539008178f * x);           // e^(2x)
    return 1.0f - 2.0f * __builtin_amdgcn_rcpf(t + 1.0f);   // -1 / +1 at the limits
}

// fused mac pinned to arch VGPRs (identical numerics to fmaf)
#define FMAC(A, W, X) asm("v_fmac_f32 %0, %1, %2" : "+v"(A) : "v"(W), "v"(X))

// ---- dtype sniffer: bf16 weights decode to |v|<=0.142; fp32-as-bf16 gives junk ----
extern "C" __global__ void sniff_dtype(const unsigned short* __restrict__ w,
                                       int* __restrict__ flag) {
    int lane = threadIdx.x;
    bool bad = false;
#pragma unroll
    for (int t = 0; t < 4; ++t) {
        float v = bf2f(w[lane * 4 + t]);
        bad |= !(fabsf(v) <= 1.0f);
    }
    unsigned long long m = __ballot(bad);
    if (lane == 0) flag[0] = (m != 0ULL) ? 1 : 0;   // 1 => fp32 buffers
}

// gate phase: thread (g, q) accumulates the K-fifth partial of gate g for all
// 8 rows. Weights in registers/AGPRs; state reads are wave-uniform LDS
// broadcasts (2-address gather in the 4 fifth-boundary waves).
template <int TQ>
__device__ __forceinline__ void gate_phase(const float* __restrict__ S,
                                           float* __restrict__ gb,
                                           const float w[TQ],
                                           int srow, int g, int q, bool active) {
    if (active) {
        float a0 = 0, a1 = 0, a2 = 0, a3 = 0, a4 = 0, a5 = 0, a6 = 0, a7 = 0;
        const float4* Sp = (const float4*)(S + (srow + q * TQ) * MROWS);
#pragma unroll
        for (int t = 0; t < TQ; ++t) {
            float wv = w[t];
            float4 lo = Sp[2 * t];         // broadcast read (rows m=0..3)
            float4 hi = Sp[2 * t + 1];     // rows m=4..7
            FMAC(a0, wv, lo.x); FMAC(a1, wv, lo.y);
            FMAC(a2, wv, lo.z); FMAC(a3, wv, lo.w);
            FMAC(a4, wv, hi.x); FMAC(a5, wv, hi.y);
            FMAC(a6, wv, hi.z); FMAC(a7, wv, hi.w);
        }
        // gb[q][m][g]: lane-consecutive scalar stores -> conflict-free
        float* d = gb + (q * MROWS) * GG + g;
        d[0 * GG] = a0; d[1 * GG] = a1; d[2 * GG] = a2; d[3 * GG] = a3;
        d[4 * GG] = a4; d[5 * GG] = a5; d[6 * GG] = a6; d[7 * GG] = a7;
    }
}

__device__ __forceinline__ void lstm_update(float* __restrict__ S,
                                            const float* __restrict__ gb,
                                            const float* __restrict__ bs,
                                            float& c, int hrow, int tid) {
    // caller guards tid < 400;  m = tid&7 (conflict-free h write), j = tid>>3
    int m = tid & 7;
    int j = tid >> 3;
    float ii = bs[j], ff = bs[50 + j], gg = bs[100 + j], oo = bs[150 + j];
#pragma unroll
    for (int q = 0; q < NQ; ++q) {
        // addr%32 = (8m+j)%32 across the wave -> 2-way (free)
        const float* b = gb + (q * MROWS + m) * GG;
        ii += b[j]; ff += b[50 + j]; gg += b[100 + j]; oo += b[150 + j];
    }
    float cn = fsig(ff) * c + fsig(ii) * ftanh(gg);
    c = cn;
    S[(hrow + j) * MROWS + m] = fsig(oo) * ftanh(cn);   // addr = hrow*8 + tid
}

extern "C" __global__
__attribute__((amdgpu_flat_work_group_size(NTHREADS, NTHREADS)))
__attribute__((amdgpu_waves_per_eu(4, 4)))
void lstm_persistent(const void* __restrict__ x,
                const void* __restrict__ wih1, const void* __restrict__ whh1,
                const void* __restrict__ bih1, const void* __restrict__ bhh1,
                const void* __restrict__ wih2, const void* __restrict__ whh2,
                const void* __restrict__ bih2, const void* __restrict__ bhh2,
                const void* __restrict__ wih3, const void* __restrict__ whh3,
                const void* __restrict__ bih3, const void* __restrict__ bhh3,
                const void* __restrict__ wlin, const void* __restrict__ blin,
                void* __restrict__ out, const int* __restrict__ flag,
                int T, int steps)
{
    const int tid = threadIdx.x;
    __shared__ float S[167 * MROWS];        // 0..16 x | 17..66 h1 | 67..116 h2 | 117..166 h3
    __shared__ float gb[NQ * MROWS * GG];   // [fifth][m][gate]  (32 KB)
    __shared__ float WLt[50 * PP];          // W_lin^T
    __shared__ float bs1[GG], bs2[GG], bs3[GG], bl[PP];

    const bool f32 = (flag[0] != 0);

    const int q = tid / GG;                 // K-fifth (wave-uniform except 4 boundary waves)
    const int g = tid - q * GG;             // gate index 0..199
    const bool active = (tid < NQ * GG);    // 1000 of 1024

    // ---- per-thread register weights (fp32, full precision): 54 floats ----
    float w1[TQ1], w2[TQ2], w3[TQ3];
    if (active) {
#pragma unroll
        for (int t = 0; t < TQ1; ++t) {              // cell1 K=68 (rows 68,69 zero-pad)
            int k = q * TQ1 + t;
            w1[t] = (k < 17) ? ldin(wih1, (long)g * 17 + k, f32)
                  : (k < 67) ? ldin(whh1, (long)g * 50 + (k - 17), f32)
                             : 0.0f;
        }
#pragma unroll
        for (int t = 0; t < TQ2; ++t) {              // cell2 K=100
            int k = q * TQ2 + t;
            w2[t] = (k < 50) ? ldin(wih2, (long)g * 50 + k, f32)
                             : ldin(whh2, (long)g * 50 + (k - 50), f32);
        }
#pragma unroll
        for (int t = 0; t < TQ3; ++t) {              // cell3 K=100
            int k = q * TQ3 + t;
            w3[t] = (k < 50) ? ldin(wih3, (long)g * 50 + k, f32)
                             : ldin(whh3, (long)g * 50 + (k - 50), f32);
        }
    }

    // ---- stage biases, W_lin^T, zero h-state, preload x(step 0) ----
    if (tid < GG) {
        bs1[tid] = ldin(bih1, tid, f32) + ldin(bhh1, tid, f32);
        bs2[tid] = ldin(bih2, tid, f32) + ldin(bhh2, tid, f32);
        bs3[tid] = ldin(bih3, tid, f32) + ldin(bhh3, tid, f32);
    } else if (tid < GG + PP) {
        bl[tid - GG] = ldin(blin, tid - GG, f32);
    }
    for (int i = tid; i < 50 * PP; i += NTHREADS) {
        int k = i / PP, p = i - k * PP;
        WLt[i] = ldin(wlin, (long)p * 50 + k, f32);
    }
    for (int i = tid; i < 1200; i += NTHREADS) S[136 + i] = 0.0f;   // h1,h2,h3 = 0

    const long rowBase = (long)blockIdx.x * MROWS;
    const long xStride = (long)T * PP;
    if (tid < 136) {
        int m = tid / PP, p = tid - (tid / PP) * PP;
        S[p * MROWS + m] = ldin(x, (rowBase + m) * xStride + p, f32);
    }
    float c1 = 0.0f, c2 = 0.0f, c3 = 0.0f;
    __syncthreads();

    const long outStride = (long)steps * PP;
    for (int s = 0; s < steps; ++s) {
        gate_phase<TQ1>(S, gb, w1, 0, g, q, active);            // cell1: [x|h1]
        __syncthreads();
        if (tid < 400) lstm_update(S, gb, bs1, c1, 17, tid);    // write h1
        __syncthreads();
        gate_phase<TQ2>(S, gb, w2, 17, g, q, active);           // cell2: [h1|h2]
        __syncthreads();
        if (tid < 400) lstm_update(S, gb, bs2, c2, 67, tid);    // write h2
        __syncthreads();
        gate_phase<TQ3>(S, gb, w3, 67, g, q, active);           // cell3: [h2|h3]
        __syncthreads();
        if (tid < 400) lstm_update(S, gb, bs3, c3, 117, tid);   // write h3
        __syncthreads();
        // ---- linear head + output + next input (feedback or global x) ----
        if (tid < 136) {
            int m = tid / PP, p = tid - (tid / PP) * PP;
            float acc = bl[p];
#pragma unroll
            for (int k = 0; k < 50; ++k)
                acc = fmaf(WLt[k * PP + p], S[(117 + k) * MROWS + m], acc);
            long oi = (rowBase + m) * outStride + (long)s * PP + p;
            if (f32) ((float*)out)[oi] = acc;
            else     ((unsigned short*)out)[oi] = f2bf(acc);
            if (s + 1 >= T && s + 1 < steps)                    // autoregressive feedback
                S[p * MROWS + m] = acc;
        } else if (tid >= 256 && tid < 392) {
            int u = tid - 256;
            int m = u / PP, p = u - (u / PP) * PP;
            if (s + 1 < T)                                      // prefetch next x chunk
                S[p * MROWS + m] = ldin(x, (rowBase + m) * xStride + (long)(s + 1) * PP + p, f32);
        }
        __syncthreads();
    }
}

extern "C" void kernel_launch(void* const* d_in, const int* in_sizes, int n_in,
                              void* d_out, int out_size, void* d_ws, size_t ws_size,
                              hipStream_t stream) {
    (void)ws_size; (void)n_in;
    int* flag = (int*)d_ws;

    const int T     = in_sizes[0] / (BATCH * PP);   // 512
    const int steps = out_size / (BATCH * PP);      // 544

    sniff_dtype<<<1, 64, 0, stream>>>((const unsigned short*)d_in[1], flag);

    lstm_persistent<<<NBLOCKS, NTHREADS, 0, stream>>>(
        d_in[0],
        d_in[1], d_in[2], d_in[3], d_in[4],
        d_in[5], d_in[6], d_in[7], d_in[8],
        d_in[9], d_in[10], d_in[11], d_in[12],
        d_in[13], d_in[14],
        d_out, flag, T, steps);
}

// Round 6
// 3340.631 us; speedup vs baseline: 2.4616x; 1.0260x over previous
//
#include <hip/hip_runtime.h>
#include <math.h>

// LSTMPredictor: B=2048 rows, 3x LSTMCell(H=50), P=17, T=512 + 32 future steps.
// fp32 buffers (runtime-sniffed, bf16 fallback kept). One block per CU owns M=8
// batch rows for the whole 544-step recurrence.
//
// R1: thread = (single gate g, K-fifth q), 1000/1024 active; 54 weight floats.
// R2 lesson: __launch_bounds__ 2nd arg can't raise the 64-VGPR cap at 1024 thr.
// R3: amdgpu_waves_per_eu(4,4) -> unified budget 128; spill gone, 3530 us, but
//     allocator split 52 arch + 76 AGPR.
// R4 null result: pinning accumulators at point-of-use ("+v" v_fmac) left VALU
//     busy at ~10.4k cyc/SIMD/step (hand-count of real work: ~4k). If the accs'
//     HOME is an AGPR, the asm just made the read/fmac/write triple explicit.
// R5 discriminator/fix: pin register CLASSES. Weights homed in AGPRs
//     (v_accvgpr_write at init, ONE v_accvgpr_read per t, amortized over 8
//     FMACs); accumulators live as "+v" FMAC operands -> arch VGPRs. 54 a +
//     ~40 v = 94 <= 128 budget. If busy doesn't drop, the overhead theory is
//     falsified -> next: dual-block M=4 structure for barrier overlap.
// (R5 resubmit: previous run died on container acquire, not on the kernel.)

#define BATCH    2048
#define PP       17
#define HH       50
#define GG       200      // 4*H
#define MROWS    8
#define NQ       5        // K split into fifths
#define NTHREADS 1024
#define NBLOCKS  (BATCH / MROWS)   // 256
#define TQ1      14       // cell1 K=68 (x17 + h50 + pad) -> 5*14=70
#define TQ2      20       // cell2 K=100 exact
#define TQ3      20       // cell3 K=100 exact

__device__ __forceinline__ float bf2f(unsigned short u) {
    unsigned int i = ((unsigned int)u) << 16;
    float f; __builtin_memcpy(&f, &i, 4); return f;
}
__device__ __forceinline__ unsigned short f2bf(float f) {
    unsigned int i; __builtin_memcpy(&i, &f, 4);
    return (unsigned short)((i + 0x7fffu + ((i >> 16) & 1u)) >> 16);
}
__device__ __forceinline__ float ldin(const void* p, long i, bool f32) {
    return f32 ? ((const float*)p)[i] : bf2f(((const unsigned short*)p)[i]);
}
// saturation-safe fast sigmoid/tanh (v_exp_f32 + v_rcp_f32)
__device__ __forceinline__ float fsig(float x) {
    float t = exp2f(-1.44269504089f * x);          // +inf at x->-inf, 0 at x->+inf
    return __builtin_amdgcn_rcpf(1.0f + t);        // 0 / 1 at the limits
}
__device__ __forceinline__ float ftanh(float x) {
    float t = exp2f(2.88539008178f * x);           // e^(2x)
    return 1.0f - 2.0f * __builtin_amdgcn_rcpf(t + 1.0f);   // -1 / +1 at the limits
}

// register-class pinning
#define AWRITE(A, V)  asm("v_accvgpr_write_b32 %0, %1" : "=a"(A) : "v"(V))
#define AREAD(V, A)   asm("v_accvgpr_read_b32 %0, %1"  : "=v"(V) : "a"(A))
#define FMAC(A, W, X) asm("v_fmac_f32 %0, %1, %2" : "+v"(A) : "v"(W), "v"(X))

// ---- dtype sniffer: bf16 weights decode to |v|<=0.142; fp32-as-bf16 gives junk ----
extern "C" __global__ void sniff_dtype(const unsigned short* __restrict__ w,
                                       int* __restrict__ flag) {
    int lane = threadIdx.x;
    bool bad = false;
#pragma unroll
    for (int t = 0; t < 4; ++t) {
        float v = bf2f(w[lane * 4 + t]);
        bad |= !(fabsf(v) <= 1.0f);
    }
    unsigned long long m = __ballot(bad);
    if (lane == 0) flag[0] = (m != 0ULL) ? 1 : 0;   // 1 => fp32 buffers
}

// gate phase: thread (g, q) accumulates the K-fifth partial of gate g for all
// 8 rows. Weights homed in AGPRs (1 accvgpr_read per t, amortized over 8
// FMACs); state reads are wave-uniform LDS broadcasts.
template <int TQ>
__device__ __forceinline__ void gate_phase(const float* __restrict__ S,
                                           float* __restrict__ gb,
                                           const float (&w)[TQ],
                                           int srow, int g, int q, bool active) {
    if (active) {
        float a0 = 0, a1 = 0, a2 = 0, a3 = 0, a4 = 0, a5 = 0, a6 = 0, a7 = 0;
        const float4* Sp = (const float4*)(S + (srow + q * TQ) * MROWS);
#pragma unroll
        for (int t = 0; t < TQ; ++t) {
            float wv; AREAD(wv, w[t]);     // AGPR -> VGPR, once per 8 FMACs
            float4 lo = Sp[2 * t];         // broadcast read (rows m=0..3)
            float4 hi = Sp[2 * t + 1];     // rows m=4..7
            FMAC(a0, wv, lo.x); FMAC(a1, wv, lo.y);
            FMAC(a2, wv, lo.z); FMAC(a3, wv, lo.w);
            FMAC(a4, wv, hi.x); FMAC(a5, wv, hi.y);
            FMAC(a6, wv, hi.z); FMAC(a7, wv, hi.w);
        }
        // gb[q][m][g]: lane-consecutive scalar stores -> conflict-free
        float* d = gb + (q * MROWS) * GG + g;
        d[0 * GG] = a0; d[1 * GG] = a1; d[2 * GG] = a2; d[3 * GG] = a3;
        d[4 * GG] = a4; d[5 * GG] = a5; d[6 * GG] = a6; d[7 * GG] = a7;
    }
}

__device__ __forceinline__ void lstm_update(float* __restrict__ S,
                                            const float* __restrict__ gb,
                                            const float* __restrict__ bs,
                                            float& c, int hrow, int tid) {
    // caller guards tid < 400;  m = tid&7 (conflict-free h write), j = tid>>3
    int m = tid & 7;
    int j = tid >> 3;
    float ii = bs[j], ff = bs[50 + j], gg = bs[100 + j], oo = bs[150 + j];
#pragma unroll
    for (int q = 0; q < NQ; ++q) {
        // addr%32 = (8m+j)%32 across the wave -> 2-way (free)
        const float* b = gb + (q * MROWS + m) * GG;
        ii += b[j]; ff += b[50 + j]; gg += b[100 + j]; oo += b[150 + j];
    }
    float cn = fsig(ff) * c + fsig(ii) * ftanh(gg);
    c = cn;
    S[(hrow + j) * MROWS + m] = fsig(oo) * ftanh(cn);   // addr = hrow*8 + tid
}

extern "C" __global__
__attribute__((amdgpu_flat_work_group_size(NTHREADS, NTHREADS)))
__attribute__((amdgpu_waves_per_eu(4, 4)))
void lstm_persistent(const void* __restrict__ x,
                const void* __restrict__ wih1, const void* __restrict__ whh1,
                const void* __restrict__ bih1, const void* __restrict__ bhh1,
                const void* __restrict__ wih2, const void* __restrict__ whh2,
                const void* __restrict__ bih2, const void* __restrict__ bhh2,
                const void* __restrict__ wih3, const void* __restrict__ whh3,
                const void* __restrict__ bih3, const void* __restrict__ bhh3,
                const void* __restrict__ wlin, const void* __restrict__ blin,
                void* __restrict__ out, const int* __restrict__ flag,
                int T, int steps)
{
    const int tid = threadIdx.x;
    __shared__ float S[167 * MROWS];        // 0..16 x | 17..66 h1 | 67..116 h2 | 117..166 h3
    __shared__ float gb[NQ * MROWS * GG];   // [fifth][m][gate]  (32 KB)
    __shared__ float WLt[50 * PP];          // W_lin^T
    __shared__ float bs1[GG], bs2[GG], bs3[GG], bl[PP];

    const bool f32 = (flag[0] != 0);

    const int q = tid / GG;                 // K-fifth (wave-uniform except 4 boundary waves)
    const int g = tid - q * GG;             // gate index 0..199
    const bool active = (tid < NQ * GG);    // 1000 of 1024

    // ---- per-thread weights homed in AGPRs (fp32, full precision): 54 ----
    float w1[TQ1], w2[TQ2], w3[TQ3];
    if (active) {
#pragma unroll
        for (int t = 0; t < TQ1; ++t) {              // cell1 K=68 (rows 68,69 zero-pad)
            int k = q * TQ1 + t;
            float v = (k < 17) ? ldin(wih1, (long)g * 17 + k, f32)
                    : (k < 67) ? ldin(whh1, (long)g * 50 + (k - 17), f32)
                               : 0.0f;
            AWRITE(w1[t], v);
        }
#pragma unroll
        for (int t = 0; t < TQ2; ++t) {              // cell2 K=100
            int k = q * TQ2 + t;
            float v = (k < 50) ? ldin(wih2, (long)g * 50 + k, f32)
                               : ldin(whh2, (long)g * 50 + (k - 50), f32);
            AWRITE(w2[t], v);
        }
#pragma unroll
        for (int t = 0; t < TQ3; ++t) {              // cell3 K=100
            int k = q * TQ3 + t;
            float v = (k < 50) ? ldin(wih3, (long)g * 50 + k, f32)
                               : ldin(whh3, (long)g * 50 + (k - 50), f32);
            AWRITE(w3[t], v);
        }
    }

    // ---- stage biases, W_lin^T, zero h-state, preload x(step 0) ----
    if (tid < GG) {
        bs1[tid] = ldin(bih1, tid, f32) + ldin(bhh1, tid, f32);
        bs2[tid] = ldin(bih2, tid, f32) + ldin(bhh2, tid, f32);
        bs3[tid] = ldin(bih3, tid, f32) + ldin(bhh3, tid, f32);
    } else if (tid < GG + PP) {
        bl[tid - GG] = ldin(blin, tid - GG, f32);
    }
    for (int i = tid; i < 50 * PP; i += NTHREADS) {
        int k = i / PP, p = i - k * PP;
        WLt[i] = ldin(wlin, (long)p * 50 + k, f32);
    }
    for (int i = tid; i < 1200; i += NTHREADS) S[136 + i] = 0.0f;   // h1,h2,h3 = 0

    const long rowBase = (long)blockIdx.x * MROWS;
    const long xStride = (long)T * PP;
    if (tid < 136) {
        int m = tid / PP, p = tid - (tid / PP) * PP;
        S[p * MROWS + m] = ldin(x, (rowBase + m) * xStride + p, f32);
    }
    float c1 = 0.0f, c2 = 0.0f, c3 = 0.0f;
    __syncthreads();

    const long outStride = (long)steps * PP;
    for (int s = 0; s < steps; ++s) {
        gate_phase<TQ1>(S, gb, w1, 0, g, q, active);            // cell1: [x|h1]
        __syncthreads();
        if (tid < 400) lstm_update(S, gb, bs1, c1, 17, tid);    // write h1
        __syncthreads();
        gate_phase<TQ2>(S, gb, w2, 17, g, q, active);           // cell2: [h1|h2]
        __syncthreads();
        if (tid < 400) lstm_update(S, gb, bs2, c2, 67, tid);    // write h2
        __syncthreads();
        gate_phase<TQ3>(S, gb, w3, 67, g, q, active);           // cell3: [h2|h3]
        __syncthreads();
        if (tid < 400) lstm_update(S, gb, bs3, c3, 117, tid);   // write h3
        __syncthreads();
        // ---- linear head + output + next input (feedback or global x) ----
        if (tid < 136) {
            int m = tid / PP, p = tid - (tid / PP) * PP;
            float acc = bl[p];
#pragma unroll
            for (int k = 0; k < 50; ++k)
                acc = fmaf(WLt[k * PP + p], S[(117 + k) * MROWS + m], acc);
            long oi = (rowBase + m) * outStride + (long)s * PP + p;
            if (f32) ((float*)out)[oi] = acc;
            else     ((unsigned short*)out)[oi] = f2bf(acc);
            if (s + 1 >= T && s + 1 < steps)                    // autoregressive feedback
                S[p * MROWS + m] = acc;
        } else if (tid >= 256 && tid < 392) {
            int u = tid - 256;
            int m = u / PP, p = u - (u / PP) * PP;
            if (s + 1 < T)                                      // prefetch next x chunk
                S[p * MROWS + m] = ldin(x, (rowBase + m) * xStride + (long)(s + 1) * PP + p, f32);
        }
        __syncthreads();
    }
}

extern "C" void kernel_launch(void* const* d_in, const int* in_sizes, int n_in,
                              void* d_out, int out_size, void* d_ws, size_t ws_size,
                              hipStream_t stream) {
    (void)ws_size; (void)n_in;
    int* flag = (int*)d_ws;

    const int T     = in_sizes[0] / (BATCH * PP);   // 512
    const int steps = out_size / (BATCH * PP);      // 544

    sniff_dtype<<<1, 64, 0, stream>>>((const unsigned short*)d_in[1], flag);

    lstm_persistent<<<NBLOCKS, NTHREADS, 0, stream>>>(
        d_in[0],
        d_in[1], d_in[2], d_in[3], d_in[4],
        d_in[5], d_in[6], d_in[7], d_in[8],
        d_in[9], d_in[10], d_in[11], d_in[12],
        d_in[13], d_in[14],
        d_out, flag, T, steps);
}